// Round 3
// baseline (133.608 us; speedup 1.0000x reference)
//
#include <hip/hip_runtime.h>
#include <hip/hip_bf16.h>
#include <math.h>

// Problem constants (B=8, T=1024, C=32, F=256, D=128, K=512)
#define N_POS 8192      // B*T
#define D_DIM 128
#define K_DIM 512
#define C_DIM 32
#define F_DIM 256
#define NKT   4         // k-tiles (128 wide each)
#define GREC_COLS 8448  // 32*256 g_rec + 256 S
#define L2_BLOCKS 388   // 256 sse + 128 grec + 4 S
#define NN_BLOCKS 512   // 128 pos-tiles (64 wide) x 4 k-tiles (128 wide)

// ---------------------------------------------------------------- reductions
__device__ __forceinline__ float block_reduce_256(float v) {
    __shared__ float sbuf[4];
    __syncthreads();
#pragma unroll
    for (int off = 32; off > 0; off >>= 1) v += __shfl_down(v, off);
    const int lane = threadIdx.x & 63;
    const int w    = threadIdx.x >> 6;
    if (lane == 0) sbuf[w] = v;
    __syncthreads();
    return (threadIdx.x == 0) ? (sbuf[0] + sbuf[1] + sbuf[2] + sbuf[3]) : 0.f;
}

// =====================  L1: XG (blocks 0..255) + NN (256..767)  =============
// R3: latency attack (R1/R2 showed more waves don't help; stalls are
// structural). (1) XG dispatched FIRST so it overlaps the NN bulk instead
// of being a low-occupancy tail. (2) NN staging is issue-early/write-late
// (T14): next-chunk global loads are issued right after the panel barrier
// and stay in flight across the ~4K-cycle compute phase, so the per-chunk
// vmcnt(0) drain at the next barrier is free. (3) grec loop gets a 2-deep
// Hdec prefetch, removing its per-iteration load->use vmcnt(0) stall.
// NN math identical to R2 (64 pos x 128 k, acc[4][8], lexicographic argmin).
__global__ __launch_bounds__(256)
void fused_l1(const float* __restrict__ H, const float* __restrict__ M,
              const float* __restrict__ Hdec, const float* __restrict__ W,
              const float* __restrict__ X, const float* __restrict__ w_d,
              float* __restrict__ MT, float* __restrict__ pd,
              int* __restrict__ pi, float* __restrict__ pp,
              float* __restrict__ accum) {
    __shared__ __align__(16) char smem_raw[38912];
    const int tid = threadIdx.x;

    if (blockIdx.x >= 256) {
        // ------------------------------- NN tile -------------------------------
        float* hT = (float*)smem_raw;        // [32][64]  (8KB)
        float* mT = hT + 2048;               // [32][128] (16KB)
        float* rd = hT;                      // [16][64] alias (after compute)
        int*   ri = (int*)(hT + 1024);       // [16][64] alias

        const int nb    = blockIdx.x - 256;
        const int ptile = nb >> 2;           // 128 pos-tiles (64 wide)
        const int ktile = nb & 3;            // 4 k-tiles (128 wide)
        const int pos0  = ptile << 6;
        const int b     = pos0 >> 10;
        const int t0    = pos0 & 1023;
        const int k0    = ktile << 7;
        const float* Hb = H + (b << 17) + t0;

        const int p4 = (tid & 15) << 2;      // compute pos quad (0..60)
        const int q4 = (tid >> 4) << 2;      // compute k quad   (0..60)

        // staging: lane-linear LDS layout (dest = base + tid*4 floats per pass)
        const float* hsrc = Hb + (size_t)(tid >> 4) * 1024 + ((tid & 15) << 2);
        const float* msrc = M  + (size_t)(tid >> 5) * K_DIM + k0 + ((tid & 31) << 2);
        float* hdst = hT + (tid << 2);
        float* mdst = mT + (tid << 2);

        float4 rh[2][2], rm[2][4];
#define LDCH(P, CH) do {                                                      \
        rh[P][0] = *(const float4*)(hsrc + (size_t)((CH)*32 +  0) * 1024);    \
        rh[P][1] = *(const float4*)(hsrc + (size_t)((CH)*32 + 16) * 1024);    \
        rm[P][0] = *(const float4*)(msrc + (size_t)((CH)*32 +  0) * 512);     \
        rm[P][1] = *(const float4*)(msrc + (size_t)((CH)*32 +  8) * 512);     \
        rm[P][2] = *(const float4*)(msrc + (size_t)((CH)*32 + 16) * 512);     \
        rm[P][3] = *(const float4*)(msrc + (size_t)((CH)*32 + 24) * 512);     \
    } while (0)
#define STCH(P) do {                                                          \
        *(float4*)(hdst)        = rh[P][0];                                   \
        *(float4*)(hdst + 1024) = rh[P][1];                                   \
        *(float4*)(mdst)        = rm[P][0];                                   \
        *(float4*)(mdst + 1024) = rm[P][1];                                   \
        *(float4*)(mdst + 2048) = rm[P][2];                                   \
        *(float4*)(mdst + 3072) = rm[P][3];                                   \
    } while (0)

        float acc[4][8];
#pragma unroll
        for (int i = 0; i < 4; ++i)
#pragma unroll
            for (int j = 0; j < 8; ++j) acc[i][j] = 0.f;

        // 32 abs-accumulates from one (h-quad, m-quad-pair) fragment set
        auto absacc32 = [&](const float4& A,
                            const float4& Ma, const float4& Mc) {
            const float hh[4] = {A.x,  A.y,  A.z,  A.w};
            const float mm[8] = {Ma.x, Ma.y, Ma.z, Ma.w, Mc.x, Mc.y, Mc.z, Mc.w};
#pragma unroll
            for (int i = 0; i < 4; ++i)
#pragma unroll
                for (int j = 0; j < 8; ++j) {
                    const float dv = hh[i] - mm[j];
                    asm("v_add_f32 %0, %0, abs(%1)"
                        : "+v"(acc[i][j]) : "v"(dv));
                }
        };

        const float* hrow = hT + p4;
        const float* mrow = mT + q4;

        LDCH(0, 0);                          // prologue loads, in flight
#pragma unroll
        for (int ch = 0; ch < 4; ++ch) {
            __syncthreads();                 // prev-chunk readers done
            if (ch & 1) STCH(1); else STCH(0);
            __syncthreads();                 // panel visible
            // issue NEXT chunk's globals now -> in flight across compute
            if (ch == 0) LDCH(1, 1);
            else if (ch == 1) LDCH(0, 2);
            else if (ch == 2) LDCH(1, 3);

            // software-pipelined d-loop: fetch row d+1 before computing row d
            float4 ha = *(const float4*)(hrow);
            float4 ma = *(const float4*)(mrow);
            float4 mc = *(const float4*)(mrow + 64);
#pragma unroll 2
            for (int d = 0; d < 31; ++d) {
                const float4 nha = *(const float4*)(hrow + ((d + 1) << 6));
                const float4 nma = *(const float4*)(mrow + ((d + 1) << 7));
                const float4 nmc = *(const float4*)(mrow + ((d + 1) << 7) + 64);
                absacc32(ha, ma, mc);
                ha = nha; ma = nma; mc = nmc;
            }
            absacc32(ha, ma, mc);            // d = 31 (peeled)
        }
#undef LDCH
#undef STCH

        __syncthreads();   // all reads of hT done before aliasing as rd/ri

        // per-thread argmin over its 8 ks (j ascending = k ascending; strict <)
#pragma unroll
        for (int i = 0; i < 4; ++i) {
            const int pl = p4 + i;           // local pos 0..63
            float bd = acc[i][0];
            int   bj = 0;
#pragma unroll
            for (int j = 1; j < 8; ++j)
                if (acc[i][j] < bd) { bd = acc[i][j]; bj = j; }
            const int bk = k0 + ((bj < 4) ? (q4 + bj) : (64 + q4 + bj - 4));
            rd[(tid >> 4) * 64 + pl] = bd;
            ri[(tid >> 4) * 64 + pl] = bk;
        }
        __syncthreads();

        // cross-thread merge: 16 k-groups, lexicographic (dist, k)
        if (tid < 64) {
            float bd = rd[tid];
            int   bi = ri[tid];
#pragma unroll
            for (int q = 1; q < 16; ++q) {
                const float d = rd[q * 64 + tid];
                const int   k = ri[q * 64 + tid];
                if (d < bd || (d == bd && k < bi)) { bd = d; bi = k; }
            }
            pd[ktile * N_POS + pos0 + tid] = bd;
            pi[ktile * N_POS + pos0 + tid] = bi;
        }
    } else {
        // --------------------- XHAT + E(LDS) + GREC partials -------------------
        float* Wl = (float*)smem_raw;        // [32][260]
        float* El = Wl + C_DIM * 260;        // [32][32]
        const int xb  = blockIdx.x;          // 0..255 (XG dispatched first)
        const int bt0 = xb << 5;

        // first 64 xg blocks transpose one 2-d x 512-k slab of M into MT
        if (xb < 64) {
            const int d0 = xb << 1;          // 2 d-rows per block, 512 k each
            const int d  = d0 + (tid >> 7);
            const int k  = (tid & 127) << 2;
#pragma unroll
            for (int j = 0; j < 4; ++j)
                MT[(size_t)(k + j) * D_DIM + d] = M[(size_t)d * K_DIM + k + j];
        }

        // stage W into LDS (stride 260)
#pragma unroll
        for (int it = 0; it < 8; ++it) {
            const int i = it * 1024 + tid * 4;
            const float4 v = *(const float4*)(W + i);
            *(float4*)(Wl + (i >> 8) * 260 + (i & 255)) = v;
        }
        __syncthreads();

        const int c  = tid & 31;
        const int rg = tid >> 5;
        const int r0 = bt0 + rg, r1 = r0 + 8, r2 = r0 + 16, r3 = r0 + 24;

        float a0 = 0.f, a1 = 0.f, a2 = 0.f, a3 = 0.f;
#pragma unroll 4
        for (int f0 = 0; f0 < F_DIM; f0 += 4) {
            const float4 w4 = *(const float4*)(Wl + c * 260 + f0);
            const float4 h0 = *(const float4*)(Hdec + (size_t)r0 * F_DIM + f0);
            const float4 h1 = *(const float4*)(Hdec + (size_t)r1 * F_DIM + f0);
            const float4 h2 = *(const float4*)(Hdec + (size_t)r2 * F_DIM + f0);
            const float4 h3 = *(const float4*)(Hdec + (size_t)r3 * F_DIM + f0);
            a0 += h0.x * w4.x + h0.y * w4.y + h0.z * w4.z + h0.w * w4.w;
            a1 += h1.x * w4.x + h1.y * w4.y + h1.z * w4.z + h1.w * w4.w;
            a2 += h2.x * w4.x + h2.y * w4.y + h2.z * w4.z + h2.w * w4.w;
            a3 += h3.x * w4.x + h3.y * w4.y + h3.z * w4.z + h3.w * w4.w;
        }

        const float wd = w_d[c];
        const float e0 = a0 - X[(size_t)r0 * C_DIM + c];
        const float e1 = a1 - X[(size_t)r1 * C_DIM + c];
        const float e2 = a2 - X[(size_t)r2 * C_DIM + c];
        const float e3 = a3 - X[(size_t)r3 * C_DIM + c];
        El[(rg)      * 32 + c] = e0;
        El[(rg + 8)  * 32 + c] = e1;
        El[(rg + 16) * 32 + c] = e2;
        El[(rg + 24) * 32 + c] = e3;
        const float sse = e0 * e0 + e1 * e1 + e2 * e2 + e3 * e3;
        const float dp  = (a0 + a1 + a2 + a3) * wd;
        const float rA = block_reduce_256(sse);
        if (tid == 0) atomicAdd(accum + 0, rA);
        const float rB = block_reduce_256(dp);
        if (tid == 0) atomicAdd(accum + 1, rB);
        __syncthreads();   // El fully visible

        // grec: thread = f; E rows via LDS float4 broadcast.
        // 2-deep Hdec prefetch removes the per-iter load->use vmcnt stall.
        const int f = tid;
        const float* hp = Hdec + (size_t)bt0 * F_DIM + f;
        float gacc[C_DIM];
#pragma unroll
        for (int cc = 0; cc < C_DIM; ++cc) gacc[cc] = 0.f;
        float sf = 0.f;
        float hd0 = hp[0];
        float hd1 = hp[F_DIM];
#pragma unroll 1
        for (int i = 0; i < 30; ++i) {
            const float hdn = hp[(size_t)(i + 2) * F_DIM];
            sf += hd0;
#pragma unroll
            for (int c4 = 0; c4 < 8; ++c4) {
                const float4 e4 = *(const float4*)(El + i * 32 + c4 * 4);
                gacc[c4 * 4 + 0] += e4.x * hd0;
                gacc[c4 * 4 + 1] += e4.y * hd0;
                gacc[c4 * 4 + 2] += e4.z * hd0;
                gacc[c4 * 4 + 3] += e4.w * hd0;
            }
            hd0 = hd1; hd1 = hdn;
        }
#pragma unroll
        for (int i = 30; i < 32; ++i) {
            sf += hd0;
#pragma unroll
            for (int c4 = 0; c4 < 8; ++c4) {
                const float4 e4 = *(const float4*)(El + i * 32 + c4 * 4);
                gacc[c4 * 4 + 0] += e4.x * hd0;
                gacc[c4 * 4 + 1] += e4.y * hd0;
                gacc[c4 * 4 + 2] += e4.z * hd0;
                gacc[c4 * 4 + 3] += e4.w * hd0;
            }
            hd0 = hd1;
        }
        float* o = pp + (size_t)xb * GREC_COLS;
#pragma unroll
        for (int cc = 0; cc < C_DIM; ++cc) o[cc * F_DIM + f] = gacc[cc];
        o[8192 + f] = sf;
    }
}

// ============ L2: merge+SSE (0..255), norm reduce (256..387), assemble ======
__global__ __launch_bounds__(256)
void fused_l2(const float* __restrict__ H, const float* __restrict__ MT,
              const float* __restrict__ pd, const int* __restrict__ pi,
              const float* __restrict__ pp, const float* __restrict__ w_d,
              float* __restrict__ accum, float* __restrict__ out) {
    const int tid = threadIdx.x;
    if (blockIdx.x < 256) {
        // ---------------- chunk-merge + memory-loss SSE ----------------
        const int bx = blockIdx.x & 31;      // pos-block
        const int by = blockIdx.x >> 5;      // d-slice 0..7
        const int pos = bx * 256 + tid;
        const int b = pos >> 10;
        const int t = pos & 1023;

        // H loads are independent of the merge -> issue them FIRST (MLP)
        const int d0 = by * 16;
        const float* Hb = H + (b << 17) + t + (d0 << 10);
        float hv[16];
#pragma unroll
        for (int j = 0; j < 16; ++j) hv[j] = Hb[j << 10];

        float bd = INFINITY;
        int   bi = 0x7fffffff;
#pragma unroll
        for (int p = 0; p < NKT; ++p) {
            const float d = pd[p * N_POS + pos];
            const int   k = pi[p * N_POS + pos];
            if (d < bd || (d == bd && k < bi)) { bd = d; bi = k; }
        }

        const float* z  = MT + (size_t)bi * D_DIM + d0;
        const float4 z0 = *(const float4*)(z);
        const float4 z1 = *(const float4*)(z + 4);
        const float4 z2 = *(const float4*)(z + 8);
        const float4 z3 = *(const float4*)(z + 12);
        float s0 = 0.f, s1 = 0.f, s2 = 0.f, s3 = 0.f;
        float e;
        e = hv[0]  - z0.x; s0 += e * e;
        e = hv[1]  - z0.y; s1 += e * e;
        e = hv[2]  - z0.z; s2 += e * e;
        e = hv[3]  - z0.w; s3 += e * e;
        e = hv[4]  - z1.x; s0 += e * e;
        e = hv[5]  - z1.y; s1 += e * e;
        e = hv[6]  - z1.z; s2 += e * e;
        e = hv[7]  - z1.w; s3 += e * e;
        e = hv[8]  - z2.x; s0 += e * e;
        e = hv[9]  - z2.y; s1 += e * e;
        e = hv[10] - z2.z; s2 += e * e;
        e = hv[11] - z2.w; s3 += e * e;
        e = hv[12] - z3.x; s0 += e * e;
        e = hv[13] - z3.y; s1 += e * e;
        e = hv[14] - z3.z; s2 += e * e;
        e = hv[15] - z3.w; s3 += e * e;
        const float r = block_reduce_256((s0 + s1) + (s2 + s3));
        if (tid == 0) atomicAdd(accum + 2, r);
    } else {
        // ---------------- norm reductions over pp ----------------
        const int g = blockIdx.x - 256;                // 0..131
        const int col = (g < 128) ? (g * 64 + (tid & 63))
                                  : (8192 + (g - 128) * 64 + (tid & 63));
        const int pc  = tid >> 6;                      // 0..3
        const float* base = pp + (size_t)(pc * 64) * GREC_COLS + col;
        float s = 0.f;
#pragma unroll 8
        for (int p = 0; p < 64; ++p) s += base[(size_t)p * GREC_COLS];
        __shared__ float red[4][64];
        red[pc][tid & 63] = s;
        __syncthreads();
        if (tid < 64) {
            const float tot = red[0][tid] + red[1][tid] +
                              red[2][tid] + red[3][tid];
            float v = tot * tot;
#pragma unroll
            for (int off = 32; off > 0; off >>= 1) v += __shfl_down(v, off);
            if (tid == 0)
                atomicAdd(accum + ((g >= 128) ? 4 : 3), v);
        }
    }

    // ---- last block to finish assembles the scalar (R4-validated) ----
    __shared__ int is_last;
    if (tid == 0) {
        __threadfence();
        unsigned int* cnt = (unsigned int*)(accum + 5);
        is_last = (atomicAdd(cnt, 1u) == L2_BLOCKS - 1);
    }
    __syncthreads();
    if (is_last && tid < 64) {
        float wd2 = (tid < C_DIM) ? w_d[tid] * w_d[tid] : 0.f;
#pragma unroll
        for (int off = 32; off > 0; off >>= 1) wd2 += __shfl_down(wd2, off);
        if (tid == 0) {
            __threadfence();
            const float sse_rec = atomicAdd(accum + 0, 0.f);
            const float dsum    = atomicAdd(accum + 1, 0.f);
            const float sse_mem = atomicAdd(accum + 2, 0.f);
            const float g2      = atomicAdd(accum + 3, 0.f);
            const float s2      = atomicAdd(accum + 4, 0.f);
            const float loss_rec = sse_rec / 262144.f;         // /(B*T*C)
            const float loss_d   = -dsum / 8192.f;             // -mean over B*T
            const float loss_m   = 2.f * sse_mem / 1048576.f;  // 2*SSE/(B*D*T)
            const float ngrec    = (2.f / 262144.f) * sqrtf(g2);
            const float ngd      = sqrtf(wd2 * s2) / 8192.f;
            const float lmbda    = ngrec / (ngd + 1e-6f);
            out[0] = loss_rec + loss_m + lmbda * loss_d;       // ALPHA = 1
        }
    }
}

// ---------------------------------------------------------------- launcher
extern "C" void kernel_launch(void* const* d_in, const int* in_sizes, int n_in,
                              void* d_out, int out_size, void* d_ws, size_t ws_size,
                              hipStream_t stream) {
    const float* X    = (const float*)d_in[0];   // [8,1024,32]
    const float* H    = (const float*)d_in[1];   // [8,128,1024]
    const float* M    = (const float*)d_in[2];   // [128,512]
    const float* Hdec = (const float*)d_in[3];   // [8,1024,256]
    const float* W    = (const float*)d_in[4];   // [32,256]
    const float* w_d  = (const float*)d_in[5];   // [32]

    float* ws    = (float*)d_ws;
    float* MT    = ws;                      // 65536 floats
    float* accum = ws + 65536;              // 16 (counter at [5])
    float* pd    = ws + 65552;              // 4*8192 = 32768
    int*   pi    = (int*)(ws + 98320);      // 32768
    float* pp    = ws + 131088;             // 256*8448 = 2162688  (~9.2 MB total)

    hipMemsetAsync(accum, 0, 16 * sizeof(float), stream);
    fused_l1<<<768,       256, 0, stream>>>(H, M, Hdec, W, X, w_d,
                                            MT, pd, pi, pp, accum);
    fused_l2<<<L2_BLOCKS, 256, 0, stream>>>(H, MT, pd, pi, pp, w_d,
                                            accum, (float*)d_out);
}

// Round 5
// 123.424 us; speedup vs baseline: 1.0825x; 1.0825x over previous
//
#include <hip/hip_runtime.h>
#include <hip/hip_bf16.h>
#include <math.h>

// Problem constants (B=8, T=1024, C=32, F=256, D=128, K=512)
#define N_POS 8192      // B*T
#define D_DIM 128
#define K_DIM 512
#define C_DIM 32
#define F_DIM 256
#define NKT   4         // k-tiles (128 wide each)
#define GREC_COLS 8448  // 32*256 g_rec + 256 S
#define L2_BLOCKS 388   // 256 sse + 128 grec + 4 S
#define XG_BLOCKS 256

// ---------------------------------------------------------------- reductions
__device__ __forceinline__ float block_reduce_256(float v) {
    __shared__ float sbuf[4];
    __syncthreads();
#pragma unroll
    for (int off = 32; off > 0; off >>= 1) v += __shfl_down(v, off);
    const int lane = threadIdx.x & 63;
    const int w    = threadIdx.x >> 6;
    if (lane == 0) sbuf[w] = v;
    __syncthreads();
    return (threadIdx.x == 0) ? (sbuf[0] + sbuf[1] + sbuf[2] + sbuf[3]) : 0.f;
}

// =====================  L1: XG (blocks 0..255) + NN (256..767)  =============
// R5: __launch_bounds__(256,4). R0-R3 post-mortem: with no waves/EU hint the
// compiler targeted high occupancy (VGPR_Count 56!), spilling acc[4][8] to
// AGPRs; the "+v" asm then bounced accvgpr_read/add/accvgpr_write at EVERY
// accumulate -> ~4 VALU insts/element instead of 2. That inflated stream
// (0.56*53us = 29.7us busy ~= 537M el * 4 / 64 lanes * 2cy) was the binding
// resource, which is why R1 (fewer acc), R2 (2x waves), R3 (latency hiding)
// were all null. Cap = 128 VGPR (4 waves/SIMD; 4 blocks/CU still fits LDS):
// acc stays in arch VGPRs, accumulate drops to the 2-inst/element floor.
// NN math identical to R2 (64 pos x 128 k, acc[4][8], lexicographic argmin
// -> exact first-min semantics, order-independent).
__global__ __launch_bounds__(256, 4)
void fused_l1(const float* __restrict__ H, const float* __restrict__ M,
              const float* __restrict__ Hdec, const float* __restrict__ W,
              const float* __restrict__ X, const float* __restrict__ w_d,
              float* __restrict__ MT, float* __restrict__ pd,
              int* __restrict__ pi, float* __restrict__ pp,
              float* __restrict__ accum) {
    __shared__ __align__(16) char smem_raw[38912];
    const int tid = threadIdx.x;

    if (blockIdx.x >= XG_BLOCKS) {
        // ------------------------------- NN tile -------------------------------
        float* hT = (float*)smem_raw;        // [32][64]  (8KB)
        float* mT = hT + 2048;               // [32][128] (16KB)
        float* rd = hT;                      // [16][64] alias (after compute)
        int*   ri = (int*)(hT + 1024);       // [16][64] alias

        const int nb    = blockIdx.x - XG_BLOCKS;
        const int ptile = nb >> 2;           // 128 pos-tiles (64 wide)
        const int ktile = nb & 3;            // 4 k-tiles (128 wide)
        const int pos0  = ptile << 6;
        const int b     = pos0 >> 10;
        const int t0    = pos0 & 1023;
        const int k0    = ktile << 7;
        const float* Hb = H + (b << 17) + t0;

        const int hq = (tid & 15) << 2;      // h staging col (float4), 16 groups
        const int hr = tid >> 4;             // h staging row 0..15
        const int mq = (tid & 31) << 2;      // m staging col (float4), 32 groups
        const int mr = tid >> 5;             // m staging row 0..7
        const int p4 = (tid & 15) << 2;      // compute pos quad (0..60)
        const int q4 = (tid >> 4) << 2;      // compute k quad   (0..60)

        float acc[4][8];
#pragma unroll
        for (int i = 0; i < 4; ++i)
#pragma unroll
            for (int j = 0; j < 8; ++j) acc[i][j] = 0.f;

        // 32 abs-accumulates from one (h-quad, m-quad-pair) fragment set
        auto absacc32 = [&](const float4& A,
                            const float4& Ma, const float4& Mc) {
            const float hh[4] = {A.x,  A.y,  A.z,  A.w};
            const float mm[8] = {Ma.x, Ma.y, Ma.z, Ma.w, Mc.x, Mc.y, Mc.z, Mc.w};
#pragma unroll
            for (int i = 0; i < 4; ++i)
#pragma unroll
                for (int j = 0; j < 8; ++j) {
                    const float dv = hh[i] - mm[j];
                    asm("v_add_f32 %0, %0, abs(%1)"
                        : "+v"(acc[i][j]) : "v"(dv));
                }
        };

        const float* hrow = hT + p4;
        const float* mrow = mT + q4;

        for (int ch = 0; ch < 4; ++ch) {
            const int d0 = ch << 5;
            __syncthreads();
            // stage h panel: 32 d x 64 pos (2 passes of 16 rows)
#pragma unroll
            for (int p = 0; p < 2; ++p) {
                const int d = (p << 4) + hr;
                *(float4*)(hT + (d << 6) + hq) =
                    *(const float4*)(Hb + ((size_t)(d0 + d) << 10) + hq);
            }
            // stage m panel: 32 d x 128 k (4 passes of 8 rows)
#pragma unroll
            for (int p = 0; p < 4; ++p) {
                const int d = (p << 3) + mr;
                *(float4*)(mT + (d << 7) + mq) =
                    *(const float4*)(M + (size_t)(d0 + d) * K_DIM + k0 + mq);
            }
            __syncthreads();

            // software-pipelined d-loop: fetch row d+1 before computing row d
            float4 ha = *(const float4*)(hrow);
            float4 ma = *(const float4*)(mrow);
            float4 mc = *(const float4*)(mrow + 64);
#pragma unroll 2
            for (int d = 0; d < 31; ++d) {
                const float4 nha = *(const float4*)(hrow + ((d + 1) << 6));
                const float4 nma = *(const float4*)(mrow + ((d + 1) << 7));
                const float4 nmc = *(const float4*)(mrow + ((d + 1) << 7) + 64);
                absacc32(ha, ma, mc);
                ha = nha; ma = nma; mc = nmc;
            }
            absacc32(ha, ma, mc);   // d = 31 (peeled)
        }

        __syncthreads();   // all reads of hT done before aliasing as rd/ri

        // per-thread argmin over its 8 ks (j ascending = k ascending; strict <)
#pragma unroll
        for (int i = 0; i < 4; ++i) {
            const int pl = p4 + i;           // local pos 0..63
            float bd = acc[i][0];
            int   bj = 0;
#pragma unroll
            for (int j = 1; j < 8; ++j)
                if (acc[i][j] < bd) { bd = acc[i][j]; bj = j; }
            const int bk = k0 + ((bj < 4) ? (q4 + bj) : (64 + q4 + bj - 4));
            rd[(tid >> 4) * 64 + pl] = bd;
            ri[(tid >> 4) * 64 + pl] = bk;
        }
        __syncthreads();

        // cross-thread merge: 16 k-groups, lexicographic (dist, k)
        if (tid < 64) {
            float bd = rd[tid];
            int   bi = ri[tid];
#pragma unroll
            for (int q = 1; q < 16; ++q) {
                const float d = rd[q * 64 + tid];
                const int   k = ri[q * 64 + tid];
                if (d < bd || (d == bd && k < bi)) { bd = d; bi = k; }
            }
            pd[ktile * N_POS + pos0 + tid] = bd;
            pi[ktile * N_POS + pos0 + tid] = bi;
        }
    } else {
        // --------------------- XHAT + E(LDS) + GREC partials -------------------
        float* Wl = (float*)smem_raw;        // [32][260]
        float* El = Wl + C_DIM * 260;        // [32][32]
        const int xb  = blockIdx.x;          // 0..255 (XG dispatched first)
        const int bt0 = xb << 5;

        // first 64 xg blocks transpose one 2-d x 512-k slab of M into MT
        if (xb < 64) {
            const int d0 = xb << 1;          // 2 d-rows per block, 512 k each
            const int d  = d0 + (tid >> 7);
            const int k  = (tid & 127) << 2;
#pragma unroll
            for (int j = 0; j < 4; ++j)
                MT[(size_t)(k + j) * D_DIM + d] = M[(size_t)d * K_DIM + k + j];
        }

        // stage W into LDS (stride 260)
#pragma unroll
        for (int it = 0; it < 8; ++it) {
            const int i = it * 1024 + tid * 4;
            const float4 v = *(const float4*)(W + i);
            *(float4*)(Wl + (i >> 8) * 260 + (i & 255)) = v;
        }
        __syncthreads();

        const int c  = tid & 31;
        const int rg = tid >> 5;
        const int r0 = bt0 + rg, r1 = r0 + 8, r2 = r0 + 16, r3 = r0 + 24;

        float a0 = 0.f, a1 = 0.f, a2 = 0.f, a3 = 0.f;
#pragma unroll 4
        for (int f0 = 0; f0 < F_DIM; f0 += 4) {
            const float4 w4 = *(const float4*)(Wl + c * 260 + f0);
            const float4 h0 = *(const float4*)(Hdec + (size_t)r0 * F_DIM + f0);
            const float4 h1 = *(const float4*)(Hdec + (size_t)r1 * F_DIM + f0);
            const float4 h2 = *(const float4*)(Hdec + (size_t)r2 * F_DIM + f0);
            const float4 h3 = *(const float4*)(Hdec + (size_t)r3 * F_DIM + f0);
            a0 += h0.x * w4.x + h0.y * w4.y + h0.z * w4.z + h0.w * w4.w;
            a1 += h1.x * w4.x + h1.y * w4.y + h1.z * w4.z + h1.w * w4.w;
            a2 += h2.x * w4.x + h2.y * w4.y + h2.z * w4.z + h2.w * w4.w;
            a3 += h3.x * w4.x + h3.y * w4.y + h3.z * w4.z + h3.w * w4.w;
        }

        const float wd = w_d[c];
        const float e0 = a0 - X[(size_t)r0 * C_DIM + c];
        const float e1 = a1 - X[(size_t)r1 * C_DIM + c];
        const float e2 = a2 - X[(size_t)r2 * C_DIM + c];
        const float e3 = a3 - X[(size_t)r3 * C_DIM + c];
        El[(rg)      * 32 + c] = e0;
        El[(rg + 8)  * 32 + c] = e1;
        El[(rg + 16) * 32 + c] = e2;
        El[(rg + 24) * 32 + c] = e3;
        const float sse = e0 * e0 + e1 * e1 + e2 * e2 + e3 * e3;
        const float dp  = (a0 + a1 + a2 + a3) * wd;
        const float rA = block_reduce_256(sse);
        if (tid == 0) atomicAdd(accum + 0, rA);
        const float rB = block_reduce_256(dp);
        if (tid == 0) atomicAdd(accum + 1, rB);
        __syncthreads();   // El fully visible

        // grec: thread = f; E rows via LDS float4 broadcast.
        // 2-deep Hdec prefetch removes the per-iter load->use vmcnt stall.
        const int f = tid;
        const float* hp = Hdec + (size_t)bt0 * F_DIM + f;
        float gacc[C_DIM];
#pragma unroll
        for (int cc = 0; cc < C_DIM; ++cc) gacc[cc] = 0.f;
        float sf = 0.f;
        float hd0 = hp[0];
        float hd1 = hp[F_DIM];
#pragma unroll 1
        for (int i = 0; i < 30; ++i) {
            const float hdn = hp[(size_t)(i + 2) * F_DIM];
            sf += hd0;
#pragma unroll
            for (int c4 = 0; c4 < 8; ++c4) {
                const float4 e4 = *(const float4*)(El + i * 32 + c4 * 4);
                gacc[c4 * 4 + 0] += e4.x * hd0;
                gacc[c4 * 4 + 1] += e4.y * hd0;
                gacc[c4 * 4 + 2] += e4.z * hd0;
                gacc[c4 * 4 + 3] += e4.w * hd0;
            }
            hd0 = hd1; hd1 = hdn;
        }
#pragma unroll
        for (int i = 30; i < 32; ++i) {
            sf += hd0;
#pragma unroll
            for (int c4 = 0; c4 < 8; ++c4) {
                const float4 e4 = *(const float4*)(El + i * 32 + c4 * 4);
                gacc[c4 * 4 + 0] += e4.x * hd0;
                gacc[c4 * 4 + 1] += e4.y * hd0;
                gacc[c4 * 4 + 2] += e4.z * hd0;
                gacc[c4 * 4 + 3] += e4.w * hd0;
            }
            hd0 = hd1;
        }
        float* o = pp + (size_t)xb * GREC_COLS;
#pragma unroll
        for (int cc = 0; cc < C_DIM; ++cc) o[cc * F_DIM + f] = gacc[cc];
        o[8192 + f] = sf;
    }
}

// ============ L2: merge+SSE (0..255), norm reduce (256..387), assemble ======
__global__ __launch_bounds__(256)
void fused_l2(const float* __restrict__ H, const float* __restrict__ MT,
              const float* __restrict__ pd, const int* __restrict__ pi,
              const float* __restrict__ pp, const float* __restrict__ w_d,
              float* __restrict__ accum, float* __restrict__ out) {
    const int tid = threadIdx.x;
    if (blockIdx.x < 256) {
        // ---------------- chunk-merge + memory-loss SSE ----------------
        const int bx = blockIdx.x & 31;      // pos-block
        const int by = blockIdx.x >> 5;      // d-slice 0..7
        const int pos = bx * 256 + tid;
        const int b = pos >> 10;
        const int t = pos & 1023;

        // H loads are independent of the merge -> issue them FIRST (MLP)
        const int d0 = by * 16;
        const float* Hb = H + (b << 17) + t + (d0 << 10);
        float hv[16];
#pragma unroll
        for (int j = 0; j < 16; ++j) hv[j] = Hb[j << 10];

        float bd = INFINITY;
        int   bi = 0x7fffffff;
#pragma unroll
        for (int p = 0; p < NKT; ++p) {
            const float d = pd[p * N_POS + pos];
            const int   k = pi[p * N_POS + pos];
            if (d < bd || (d == bd && k < bi)) { bd = d; bi = k; }
        }

        const float* z  = MT + (size_t)bi * D_DIM + d0;
        const float4 z0 = *(const float4*)(z);
        const float4 z1 = *(const float4*)(z + 4);
        const float4 z2 = *(const float4*)(z + 8);
        const float4 z3 = *(const float4*)(z + 12);
        float s0 = 0.f, s1 = 0.f, s2 = 0.f, s3 = 0.f;
        float e;
        e = hv[0]  - z0.x; s0 += e * e;
        e = hv[1]  - z0.y; s1 += e * e;
        e = hv[2]  - z0.z; s2 += e * e;
        e = hv[3]  - z0.w; s3 += e * e;
        e = hv[4]  - z1.x; s0 += e * e;
        e = hv[5]  - z1.y; s1 += e * e;
        e = hv[6]  - z1.z; s2 += e * e;
        e = hv[7]  - z1.w; s3 += e * e;
        e = hv[8]  - z2.x; s0 += e * e;
        e = hv[9]  - z2.y; s1 += e * e;
        e = hv[10] - z2.z; s2 += e * e;
        e = hv[11] - z2.w; s3 += e * e;
        e = hv[12] - z3.x; s0 += e * e;
        e = hv[13] - z3.y; s1 += e * e;
        e = hv[14] - z3.z; s2 += e * e;
        e = hv[15] - z3.w; s3 += e * e;
        const float r = block_reduce_256((s0 + s1) + (s2 + s3));
        if (tid == 0) atomicAdd(accum + 2, r);
    } else {
        // ---------------- norm reductions over pp ----------------
        const int g = blockIdx.x - 256;                // 0..131
        const int col = (g < 128) ? (g * 64 + (tid & 63))
                                  : (8192 + (g - 128) * 64 + (tid & 63));
        const int pc  = tid >> 6;                      // 0..3
        const float* base = pp + (size_t)(pc * 64) * GREC_COLS + col;
        float s = 0.f;
#pragma unroll 8
        for (int p = 0; p < 64; ++p) s += base[(size_t)p * GREC_COLS];
        __shared__ float red[4][64];
        red[pc][tid & 63] = s;
        __syncthreads();
        if (tid < 64) {
            const float tot = red[0][tid] + red[1][tid] +
                              red[2][tid] + red[3][tid];
            float v = tot * tot;
#pragma unroll
            for (int off = 32; off > 0; off >>= 1) v += __shfl_down(v, off);
            if (tid == 0)
                atomicAdd(accum + ((g >= 128) ? 4 : 3), v);
        }
    }

    // ---- last block to finish assembles the scalar (R4-validated) ----
    __shared__ int is_last;
    if (tid == 0) {
        __threadfence();
        unsigned int* cnt = (unsigned int*)(accum + 5);
        is_last = (atomicAdd(cnt, 1u) == L2_BLOCKS - 1);
    }
    __syncthreads();
    if (is_last && tid < 64) {
        float wd2 = (tid < C_DIM) ? w_d[tid] * w_d[tid] : 0.f;
#pragma unroll
        for (int off = 32; off > 0; off >>= 1) wd2 += __shfl_down(wd2, off);
        if (tid == 0) {
            __threadfence();
            const float sse_rec = atomicAdd(accum + 0, 0.f);
            const float dsum    = atomicAdd(accum + 1, 0.f);
            const float sse_mem = atomicAdd(accum + 2, 0.f);
            const float g2      = atomicAdd(accum + 3, 0.f);
            const float s2      = atomicAdd(accum + 4, 0.f);
            const float loss_rec = sse_rec / 262144.f;         // /(B*T*C)
            const float loss_d   = -dsum / 8192.f;             // -mean over B*T
            const float loss_m   = 2.f * sse_mem / 1048576.f;  // 2*SSE/(B*D*T)
            const float ngrec    = (2.f / 262144.f) * sqrtf(g2);
            const float ngd      = sqrtf(wd2 * s2) / 8192.f;
            const float lmbda    = ngrec / (ngd + 1e-6f);
            out[0] = loss_rec + loss_m + lmbda * loss_d;       // ALPHA = 1
        }
    }
}

// ---------------------------------------------------------------- launcher
extern "C" void kernel_launch(void* const* d_in, const int* in_sizes, int n_in,
                              void* d_out, int out_size, void* d_ws, size_t ws_size,
                              hipStream_t stream) {
    const float* X    = (const float*)d_in[0];   // [8,1024,32]
    const float* H    = (const float*)d_in[1];   // [8,128,1024]
    const float* M    = (const float*)d_in[2];   // [128,512]
    const float* Hdec = (const float*)d_in[3];   // [8,1024,256]
    const float* W    = (const float*)d_in[4];   // [32,256]
    const float* w_d  = (const float*)d_in[5];   // [32]

    float* ws    = (float*)d_ws;
    float* MT    = ws;                      // 65536 floats
    float* accum = ws + 65536;              // 16 (counter at [5])
    float* pd    = ws + 65552;              // 4*8192 = 32768
    int*   pi    = (int*)(ws + 98320);      // 32768
    float* pp    = ws + 131088;             // 256*8448 = 2162688  (~9.2 MB total)

    hipMemsetAsync(accum, 0, 16 * sizeof(float), stream);
    fused_l1<<<768,       256, 0, stream>>>(H, M, Hdec, W, X, w_d,
                                            MT, pd, pi, pp, accum);
    fused_l2<<<L2_BLOCKS, 256, 0, stream>>>(H, MT, pd, pi, pp, w_d,
                                            accum, (float*)d_out);
}